// Round 2
// baseline (307.960 us; speedup 1.0000x reference)
//
#include <hip/hip_runtime.h>

// Reference: result = items (4M x 2 x 2 x 3 fp32) copied verbatim;
//            final_pool = items[:1024] (12,288 floats) appended after it.
// Pure D2D copy, memory-bound: 192 MB read + 192 MB write = 384 MB
// -> ~61 us floor at the 6.3 TB/s achievable HBM ceiling (m13).
//
// Strategy:
//  - grid-stride loop with grid capped at 2048 blocks (8 blocks/CU x 256 CU),
//    ~23 float4 copies per thread -> amortizes scheduling, full occupancy.
//  - 32-bit indices (max byte offset ~192 MB < 2^31) -> no 64-bit addr math.
//  - nontemporal load/store: 384 MB stream > 256 MB L3, caching is pollution.
//    NOTE: must use a clang ext_vector type — the builtin rejects HIP's
//    float4 struct (HIP_vector_type). ext_vector float4 lowers to the same
//    global_load_dwordx4 / global_store_dwordx4, plus the `nt` flag.

#define N_MAIN_VEC 12000000   // 48,000,000 floats / 4
#define N_TAIL_VEC 3072       // 12,288 floats / 4
#define TOTAL_VEC  (N_MAIN_VEC + N_TAIL_VEC)

typedef float vfloat4 __attribute__((ext_vector_type(4)));

__global__ __launch_bounds__(256) void copy_kernel(const vfloat4* __restrict__ in,
                                                   vfloat4* __restrict__ out) {
    const int stride = (int)(gridDim.x * blockDim.x);
    for (int i = (int)(blockIdx.x * blockDim.x + threadIdx.x); i < TOTAL_VEC; i += stride) {
        // Tail (last 3072 vecs) re-reads the first 3072 vecs of the input.
        const int src = (i < N_MAIN_VEC) ? i : (i - N_MAIN_VEC);
        vfloat4 v = __builtin_nontemporal_load(&in[src]);
        __builtin_nontemporal_store(v, &out[i]);
    }
}

extern "C" void kernel_launch(void* const* d_in, const int* in_sizes, int n_in,
                              void* d_out, int out_size, void* d_ws, size_t ws_size,
                              hipStream_t stream) {
    const vfloat4* in = (const vfloat4*)d_in[0];
    vfloat4* out = (vfloat4*)d_out;
    const int block = 256;
    const int grid = 2048;  // 8 blocks/CU on 256 CUs; grid-stride covers the rest
    copy_kernel<<<dim3(grid), dim3(block), 0, stream>>>(in, out);
}